// Round 5
// baseline (539.088 us; speedup 1.0000x reference)
//
#include <hip/hip_runtime.h>
#include <stdint.h>

// Problem constants
#define NTOK 1024          // N*T
#define DIM  512           // D
#define NH   8             // H
#define DKH  128           // DK
#define HALFD 64           // DK/2
#define EXP  256           // E
#define EE   65536         // E*E
#define HDK  1024          // H*DK

typedef short bf16x8 __attribute__((ext_vector_type(8)));
typedef float f32x4  __attribute__((ext_vector_type(4)));

__device__ __forceinline__ unsigned short f2bf(float f) {
    unsigned u = __float_as_uint(f);
    u += 0x7fff + ((u >> 16) & 1);     // round-to-nearest-even
    return (unsigned short)(u >> 16);
}
__device__ __forceinline__ float bf2f(unsigned short h) {
    return __uint_as_float((unsigned)h << 16);
}

// sortable key: higher float -> higher key; ties -> lower index higher key
// (matches lax.top_k stable ordering exactly)
__device__ __forceinline__ unsigned long long mkkey(float x, int idx) {
    unsigned u = __float_as_uint(x);
    unsigned mu = u ^ ((unsigned)((int)u >> 31) | 0x80000000u);
    return ((unsigned long long)mu << 32) | (unsigned)(255 - idx);
}

// async global->LDS, 16B per lane (m97 ladder step)
__device__ __forceinline__ void gload16(const unsigned short* g, unsigned short* l) {
    __builtin_amdgcn_global_load_lds(
        (const __attribute__((address_space(1))) void*)g,
        (__attribute__((address_space(3))) void*)l, 16, 0, 0);
}

// combo-candidate table: (i,j) with (i+1)*(j+1) <= 16 encoded as i*16+j.
// Any combo outside this set has >= 16 strictly-greater keys (dominance +
// strict tiebreak), so the exact top-16 of the 256 sums lies inside it.
__device__ __constant__ unsigned char qtab[64] = {
    0, 1, 2, 3, 4, 5, 6, 7, 8, 9, 10, 11, 12, 13, 14, 15,   // i=0
    16, 17, 18, 19, 20, 21, 22, 23,                          // i=1
    32, 33, 34, 35, 36,                                      // i=2
    48, 49, 50, 51,                                          // i=3
    64, 65, 66,                                              // i=4
    80, 81, 96, 97, 112, 113,                                // i=5,6,7
    128, 144, 160, 176, 192, 208, 224, 240,                  // i=8..15
    0, 0, 0, 0, 0, 0, 0, 0, 0, 0, 0, 0, 0, 0};               // pad

// ---------------- fp32 -> bf16 convert (8 elems/thread) ----------------
__global__ void cvt_bf16(const float* __restrict__ src,
                         unsigned short* __restrict__ dst, int n8) {
    int i = blockIdx.x * blockDim.x + threadIdx.x;
    if (i >= n8) return;
    const float4* s4 = (const float4*)src;
    float4 a = s4[2 * i], b = s4[2 * i + 1];
    union { unsigned short u[8]; uint4 v; } r;
    r.u[0] = f2bf(a.x); r.u[1] = f2bf(a.y); r.u[2] = f2bf(a.z); r.u[3] = f2bf(a.w);
    r.u[4] = f2bf(b.x); r.u[5] = f2bf(b.y); r.u[6] = f2bf(b.z); r.u[7] = f2bf(b.w);
    ((uint4*)dst)[i] = r.v;
}

// ------- fp32 (1024x512) -> K-concat hi/lo pack (1024x1536 bf16) -------
// MODE 0 (Q):  dst row = [hi | hi | lo]
// MODE 1 (Wq): dst row = [hi | lo | hi]
template <int MODE>
__global__ void cvt_pack(const float* __restrict__ src,
                         unsigned short* __restrict__ dst) {
    int i = blockIdx.x * blockDim.x + threadIdx.x;  // float4 idx over 1024x512
    if (i >= 131072) return;
    int r = i >> 7, c4 = i & 127;
    float4 a = ((const float4*)src)[i];
    union { unsigned short u[4]; uint2 v; } rh, rl;
    float x[4] = {a.x, a.y, a.z, a.w};
#pragma unroll
    for (int j = 0; j < 4; j++) {
        unsigned short h = f2bf(x[j]);
        rh.u[j] = h;
        rl.u[j] = f2bf(x[j] - bf2f(h));
    }
    uint2* A2 = (uint2*)dst;                 // row stride 1536 shorts = 384 uint2
    A2[r * 384 + c4] = rh.v;
    A2[r * 384 + 128 + c4] = (MODE == 0) ? rh.v : rl.v;
    A2[r * 384 + 256 + c4] = (MODE == 0) ? rl.v : rh.v;
}

// ------- w_up half (32768 x 512) fp32 -> WuTh (512 x 32768) bf16 -------
// v2: 64x64 tiles, float4 global loads (256B segments), uint4 packed bf16
// stores (128B segments). LDS stride 65 floats: both phases 2-way = free.
__global__ void transpose_wu(const float* __restrict__ wu,
                             unsigned short* __restrict__ wuT, int e0base) {
    __shared__ float tile[64][65];
    int d0 = blockIdx.x * 64;          // 8 d-blocks
    int e0 = blockIdx.y * 64;          // 512 e-blocks per half
    int tid = threadIdx.x;

    int lr = tid >> 4;                 // 0..15 (e row within pass)
    int lc = tid & 15;                 // float4 col (4 d each)
#pragma unroll
    for (int p = 0; p < 4; p++) {
        int e = lr + 16 * p;
        float4 v = *(const float4*)&wu[(size_t)(e0base + e0 + e) * DIM + d0 + lc * 4];
        tile[e][lc * 4 + 0] = v.x;
        tile[e][lc * 4 + 1] = v.y;
        tile[e][lc * 4 + 2] = v.z;
        tile[e][lc * 4 + 3] = v.w;
    }
    __syncthreads();

    int dr = tid >> 3;                 // 0..31 (d row within pass)
    int ec = tid & 7;                  // e-group (8 e each)
#pragma unroll
    for (int p = 0; p < 2; p++) {
        int d = dr + 32 * p;
        union { unsigned short u[8]; uint4 v; } r;
#pragma unroll
        for (int k = 0; k < 8; k++) r.u[k] = f2bf(tile[ec * 8 + k][d]);
        *(uint4*)&wuT[(size_t)(d0 + d) * 32768 + e0 + ec * 8] = r.v;
    }
}

// ---------------- generic bf16 GEMM  C = A(MxK) * B(NxK)^T ----------------
// 128x128 tile, BK=64, 256 threads. global_load_lds width-16 staging,
// XOR source-swizzle (kchunk = slot ^ (row&7)) for conflict-free ds_read_b128.
// XCD-aware bijective block swizzle (T1): consecutive dispatched blocks land
// round-robin on the 8 XCDs; remap so each XCD gets a CONTIGUOUS logical
// chunk -> the 8 row-blocks sharing one B stripe hit the SAME XCD L2.
// Requires total blocks % 8 == 0 (all our grids: 64, 2048, 1024).
// EPI: 0 = plain store fp32 (qh)
//      1 = relu(acc)*scale[col], store bf16 (C tile); scale = w (pre-offset)
//      4 = store bf16 partial at slice bz (split-K, no atomics)
template <int EPI>
__global__ __launch_bounds__(256, 4) void gemm_bt(
    const unsigned short* __restrict__ A, int lda,
    const unsigned short* __restrict__ B, int ldb,
    int kIters,
    float* __restrict__ outF, unsigned short* __restrict__ outB, int ldc,
    const float* __restrict__ scale, size_t sliceStride) {
    __shared__ __align__(16) unsigned short As[128 * 64];
    __shared__ __align__(16) unsigned short Bs[128 * 64];

    // ---- T1 XCD swizzle ----
    int nwg = gridDim.x * gridDim.y * gridDim.z;
    int flat = blockIdx.x + gridDim.x * (blockIdx.y + gridDim.y * blockIdx.z);
    int swz;
    if ((nwg & 7) == 0) {
        int chunk = nwg >> 3;
        swz = (flat & 7) * chunk + (flat >> 3);
    } else {
        swz = flat;
    }
    int bx = swz % gridDim.x;
    int tmp = swz / gridDim.x;
    int by = tmp % gridDim.y;
    int bz = tmp / gridDim.y;

    int tid = threadIdx.x;
    int lane = tid & 63, wave = tid >> 6;
    int wm = (wave >> 1) * 64, wn = (wave & 1) * 64;
    int row0 = bx * 128, col0 = by * 128;
    size_t k00 = (size_t)bz * kIters * 64;           // split-K offset

    int rr = tid >> 3;
    int ss = tid & 7;
    int kb = ss ^ (rr & 7);
    const unsigned short* Ab = A + (size_t)(row0 + rr) * lda + k00 + kb * 8;
    const unsigned short* Bb = B + (size_t)(col0 + rr) * ldb + k00 + kb * 8;
    unsigned short* Asw = As + (size_t)tid * 8;      // lane-linear LDS dest
    unsigned short* Bsw = Bs + (size_t)tid * 8;

    f32x4 acc[4][4];
#pragma unroll
    for (int i = 0; i < 4; i++)
#pragma unroll
        for (int j = 0; j < 4; j++) acc[i][j] = 0.f;

    for (int kt = 0; kt < kIters; ++kt) {
        __syncthreads();                              // LDS consumers done
#pragma unroll
        for (int i = 0; i < 4; i++)
            gload16(Ab + (size_t)(32 * i) * lda + kt * 64, Asw + i * 2048);
#pragma unroll
        for (int i = 0; i < 4; i++)
            gload16(Bb + (size_t)(32 * i) * ldb + kt * 64, Bsw + i * 2048);
        __syncthreads();                              // vmcnt(0) drained here
#pragma unroll
        for (int ks = 0; ks < 2; ks++) {
            bf16x8 af[4], bfr[4];
#pragma unroll
            for (int i = 0; i < 4; i++) {
                int m = wm + i * 16 + (lane & 15);
                int kq = ks * 4 + (lane >> 4);
                af[i]  = *(const bf16x8*)(As + m * 64 + ((kq ^ (m & 7)) * 8));
                int n = wn + i * 16 + (lane & 15);
                bfr[i] = *(const bf16x8*)(Bs + n * 64 + ((kq ^ (n & 7)) * 8));
            }
#pragma unroll
            for (int i = 0; i < 4; i++)
#pragma unroll
                for (int j = 0; j < 4; j++)
                    acc[i][j] = __builtin_amdgcn_mfma_f32_16x16x32_bf16(
                        af[i], bfr[j], acc[i][j], 0, 0, 0);
        }
    }

    // epilogue: D[row=(lane>>4)*4+r][col=lane&15] per 16x16 tile (m89-verified)
#pragma unroll
    for (int i = 0; i < 4; i++) {
        int rbase = row0 + wm + i * 16 + (lane >> 4) * 4;
#pragma unroll
        for (int j = 0; j < 4; j++) {
            int c = col0 + wn + j * 16 + (lane & 15);
#pragma unroll
            for (int r2 = 0; r2 < 4; r2++) {
                float v = acc[i][j][r2];
                int row = rbase + r2;
                if (EPI == 0) {
                    outF[(size_t)row * ldc + c] = v;
                } else if (EPI == 1) {
                    outB[(size_t)row * ldc + c] = f2bf(fmaxf(v, 0.f) * scale[c]);
                } else {  // EPI == 4: bf16 split-K partial
                    outB[(size_t)bz * sliceStride + (size_t)row * ldc + c] =
                        f2bf(v);
                }
            }
        }
    }
}

// ---------------- sum 64 bf16 split-K partial slices -> out ----------------
__global__ void reduce_part(const unsigned short* __restrict__ part,
                            float* __restrict__ out) {
    int i = blockIdx.x * blockDim.x + threadIdx.x;   // 8-elem group, 65536 total
    const uint4* p4 = (const uint4*)part;            // 8 bf16 per uint4
    float s[8];
#pragma unroll
    for (int j = 0; j < 8; j++) s[j] = 0.f;
    for (int sl = 0; sl < 64; sl++) {
        uint4 t = p4[(size_t)sl * 65536 + i];
        unsigned uu[4] = {t.x, t.y, t.z, t.w};
#pragma unroll
        for (int j = 0; j < 4; j++) {
            s[2 * j]     += bf2f((unsigned short)(uu[j] & 0xffff));
            s[2 * j + 1] += bf2f((unsigned short)(uu[j] >> 16));
        }
    }
    float4* o4 = (float4*)out;
    o4[2 * i]     = make_float4(s[0], s[1], s[2], s[3]);
    o4[2 * i + 1] = make_float4(s[4], s[5], s[6], s[7]);
}

// ---------------- dense scores: S[nt][h][half][e] = q . k  (fp32) ----------
// block = (token-tile of 16, h, half), 256 threads = one e each.
// Key row (64 f32) lives in 16 float4 registers (issued up-front, pipelined);
// q-tile (16x64 +bias) staged in LDS, read as broadcasts.
// Accumulation expression order matches the original fused kernel exactly.
__global__ __launch_bounds__(256) void score_all(
    const float* __restrict__ qh, const float* __restrict__ bq,
    const float* __restrict__ keys, float* __restrict__ S) {
    int t0 = blockIdx.x * 16;
    int h  = blockIdx.y;
    int half = blockIdx.z;
    int tid = threadIdx.x;                       // e index

    __shared__ __align__(16) float qs[16 * 64];

    // 16 independent global loads: this thread's key row
    const float4* krow =
        (const float4*)(keys + (size_t)((h * 2 + half) * EXP + tid) * HALFD);
    float4 kreg[16];
#pragma unroll
    for (int c = 0; c < 16; c++) kreg[c] = krow[c];

    // stage q tile with bias folded in: thread i -> t=i>>4, c4=i&15
    {
        int t = tid >> 4, c4 = tid & 15;
        const float4* qsrc =
            (const float4*)(qh + (size_t)(t0 + t) * HDK + h * DKH + half * HALFD);
        const float4* bsrc = (const float4*)(bq + h * DKH + half * HALFD);
        float4 qv = qsrc[c4], bv = bsrc[c4];
        ((float4*)qs)[t * 16 + c4] =
            make_float4(qv.x + bv.x, qv.y + bv.y, qv.z + bv.z, qv.w + bv.w);
    }
    __syncthreads();

    float acc[16];
#pragma unroll
    for (int t = 0; t < 16; t++) acc[t] = 0.f;
#pragma unroll
    for (int c = 0; c < 16; c++) {
        float4 kv = kreg[c];
#pragma unroll
        for (int t = 0; t < 16; t++) {
            float4 qv = ((const float4*)qs)[t * 16 + c];   // LDS broadcast
            acc[t] += kv.x * qv.x + kv.y * qv.y + kv.z * qv.z + kv.w * qv.w;
        }
    }

#pragma unroll
    for (int t = 0; t < 16; t++)
        S[(size_t)(((t0 + t) * NH + h) * 2 + half) * EXP + tid] = acc[t];
}

// ------- exact hierarchical rank-based top-k + softmax (scores in) -------
// v2: phases 3/4 collapsed to wave 0 over the 50 dominance-feasible combos
// ((i+1)(j+1)<=16); 3 barriers total (was 7). Selection provably identical.
__global__ __launch_bounds__(256) void topk_sel(
    const float* __restrict__ S, float* __restrict__ w) {
    int nt = blockIdx.x, h = blockIdx.y;
    int tid = threadIdx.x;
    int lane = tid & 63, wv = tid >> 6;

    __shared__ __align__(16) unsigned long long sk[2 * EXP];  // key1,key2 interleaved
    __shared__ float c1v[64], c2v[64];
    __shared__ unsigned long long c1k[64], c2k[64];
    __shared__ int c1e[64], c2e[64];
    __shared__ float t1v[16], t2v[16];
    __shared__ int   t1i[16], t2i[16];
    __shared__ __align__(16) unsigned long long ck[64];
    __shared__ float selv[16];
    __shared__ int   seli[16];

    // scores precomputed by score_all (coalesced 1KB per half per block)
    float v1 = S[(size_t)((nt * NH + h) * 2 + 0) * EXP + tid];
    float v2 = S[(size_t)((nt * NH + h) * 2 + 1) * EXP + tid];
    sk[2 * tid]     = mkkey(v1, tid);
    sk[2 * tid + 1] = mkkey(v2, tid);
    __syncthreads();

    // wave-local exact top-16 by rank within own 64-segment (keys distinct)
    {
        unsigned long long k1 = sk[2 * tid], k2 = sk[2 * tid + 1];
        int r1 = 0, r2 = 0, base = wv * 64;
#pragma unroll 4
        for (int j = 0; j < 64; j++) {
            ulonglong2 p = *(const ulonglong2*)&sk[2 * (base + j)];
            r1 += (p.x > k1);
            r2 += (p.y > k2);
        }
        if (r1 < 16) { c1k[wv * 16 + r1] = k1; c1v[wv * 16 + r1] = v1; c1e[wv * 16 + r1] = tid; }
        if (r2 < 16) { c2k[wv * 16 + r2] = k2; c2v[wv * 16 + r2] = v2; c2e[wv * 16 + r2] = tid; }
    }
    __syncthreads();

    // merge 64 candidates -> global top-16 (wave0: s1, wave1: s2)
    if (wv < 2) {
        const unsigned long long* ak = wv ? c2k : c1k;
        const float* av = wv ? c2v : c1v;
        const int*   ae = wv ? c2e : c1e;
        unsigned long long mk = ak[lane];
        int r = 0;
#pragma unroll 4
        for (int j = 0; j < 64; j++) r += (ak[j] > mk);
        if (r < 16) {
            if (wv == 0) { t1v[r] = av[lane]; t1i[r] = ae[lane]; }
            else         { t2v[r] = av[lane]; t2i[r] = ae[lane]; }
        }
    }
    __syncthreads();

    // wave 0 alone: exact top-16 of the 256 combo sums via the 50-candidate
    // dominance set, then softmax + scatter. t1v/t2v are sorted desc (indexed
    // by rank), so any combo outside {(i+1)(j+1)<=16} has >=16 strictly
    // greater keys (componentwise-dominating combos have lower flat index ->
    // strictly greater mkkey on value ties). Rank within the 50 == global rank
    // for the true top-16; non-top-16 candidates see all 16 winners in-set.
    if (wv == 0) {
        int qq = (int)qtab[lane];
        bool act = lane < 50;
        float cval = t1v[qq >> 4] + t2v[qq & 15];
        unsigned long long k = act ? mkkey(cval, qq) : 0ULL;  // pad keys lose
        ck[lane] = k;
        asm volatile("s_waitcnt lgkmcnt(0)" ::: "memory");    // in-wave visibility
        int r = 0;
#pragma unroll 5
        for (int j = 0; j < 50; j += 2) {
            ulonglong2 p = *(const ulonglong2*)&ck[j];
            r += (p.x > k);
            r += (p.y > k);
        }
        if (act && r < 16) {
            selv[r] = cval;
            seli[r] = t1i[qq >> 4] * EXP + t2i[qq & 15];
        }
        asm volatile("s_waitcnt lgkmcnt(0)" ::: "memory");    // selv/seli visible
        if (lane < 16) {
            float val = selv[lane];
            float mx = selv[0];
#pragma unroll
            for (int j = 1; j < 16; j++) mx = fmaxf(mx, selv[j]);
            float sm = 0.f;
#pragma unroll
            for (int j = 0; j < 16; j++) sm += __expf(selv[j] - mx);
            atomicAdd(&w[seli[lane]], __expf(val - mx) / sm);
        }
    }
}

// ---------------- launch ----------------
extern "C" void kernel_launch(void* const* d_in, const int* in_sizes, int n_in,
                              void* d_out, int out_size, void* d_ws, size_t ws_size,
                              hipStream_t stream) {
    const float* queries = (const float*)d_in[0];   // (2,512,512)
    const float* Wq      = (const float*)d_in[1];   // (1024,512)
    const float* bq      = (const float*)d_in[2];   // (1024)
    const float* keys    = (const float*)d_in[3];   // (8,2,256,64)
    const float* wd      = (const float*)d_in[4];   // (65536,512)
    const float* wu      = (const float*)d_in[5];   // (65536,512)
    float* out = (float*)d_out;                     // (2,512,512) fp32

    // workspace layout (196 MB)
    uint8_t* ws = (uint8_t*)d_ws;
    const size_t MB = 1048576;
    unsigned short* Qcat  = (unsigned short*)(ws);            // 0..3 MB (1024x1536)
    float*          w     = (float*)(ws + 3 * MB);            // 3..3.25 MB
    unsigned short* Wdh   = (unsigned short*)(ws + 4 * MB);   // 4..36 MB (32768x512)
    unsigned short* WuTh  = (unsigned short*)(ws + 36 * MB);  // 36..68 MB (512x32768)
    unsigned short* Cb    = (unsigned short*)(ws + 68 * MB);  // 68..132 MB (1024x32768)
    unsigned short* Ppart = (unsigned short*)(ws + 132 * MB); // 132..196 MB (64 slices bf16)
    // dead-after-score buffers alias the Ppart region (stream-ordered safe)
    unsigned short* Wqcat = (unsigned short*)(ws + 132 * MB); // 3 MB
    float*          qh    = (float*)(ws + 135 * MB);          // 4 MB
    float*          S     = (float*)(ws + 139 * MB);          // 16 MB scores

    hipMemsetAsync(w, 0, EE * sizeof(float), stream);

    cvt_pack<0><<<512, 256, 0, stream>>>(queries, Qcat);
    cvt_pack<1><<<512, 256, 0, stream>>>(Wq, Wqcat);

    // qh = Q @ Wq^T in ~fp32 via single K=1536 concat GEMM (bias in score_all)
    gemm_bt<0><<<dim3(8, 8, 1), 256, 0, stream>>>(
        Qcat, 1536, Wqcat, 1536, 24, qh, nullptr, HDK, nullptr, 0);

    // dense fp32 scores, then exact top-k + softmax -> w[e]
    score_all<<<dim3(64, NH, 2), 256, 0, stream>>>(qh, bq, keys, S);
    topk_sel<<<dim3(NTOK, NH), 256, 0, stream>>>(S, w);

    // big GEMMs per e-half; converts reuse 32 MB buffers inside the loop
    for (int sp = 0; sp < 2; sp++) {
        cvt_bf16<<<8192, 256, 0, stream>>>(wd + (size_t)sp * 16777216, Wdh, 2097152);
        // C[t,e] = relu(Q . wd[e]) * w[e]   (M=1024, N=32768, K=512)
        gemm_bt<1><<<dim3(8, 256, 1), 256, 0, stream>>>(
            Qcat, 1536, Wdh, DIM, 8, nullptr, Cb, 32768, w + (size_t)sp * 32768, 0);
        transpose_wu<<<dim3(8, 512), 256, 0, stream>>>(wu, WuTh, sp * 32768);
        // partial[z][t,d] = C[t,z-slice] . WuT[d,z-slice]  (split-K=32/half, bf16)
        gemm_bt<4><<<dim3(8, 4, 32), 256, 0, stream>>>(
            Cb, 32768, WuTh, 32768, 16, nullptr,
            Ppart + (size_t)sp * 32 * 524288, DIM, nullptr, 524288);
    }
    // out = sum of 64 bf16 partial slices
    reduce_part<<<256, 256, 0, stream>>>(Ppart, out);
}

// Round 6
// 524.674 us; speedup vs baseline: 1.0275x; 1.0275x over previous
//
#include <hip/hip_runtime.h>
#include <stdint.h>

// Problem constants
#define NTOK 1024          // N*T
#define DIM  512           // D
#define NH   8             // H
#define DKH  128           // DK
#define HALFD 64           // DK/2
#define EXP  256           // E
#define EE   65536         // E*E
#define HDK  1024          // H*DK

typedef short bf16x8 __attribute__((ext_vector_type(8)));
typedef float f32x4  __attribute__((ext_vector_type(4)));

__device__ __forceinline__ unsigned short f2bf(float f) {
    unsigned u = __float_as_uint(f);
    u += 0x7fff + ((u >> 16) & 1);     // round-to-nearest-even
    return (unsigned short)(u >> 16);
}
__device__ __forceinline__ float bf2f(unsigned short h) {
    return __uint_as_float((unsigned)h << 16);
}

// sortable key: higher float -> higher key; ties -> lower index higher key
// (matches lax.top_k stable ordering exactly)
__device__ __forceinline__ unsigned long long mkkey(float x, int idx) {
    unsigned u = __float_as_uint(x);
    unsigned mu = u ^ ((unsigned)((int)u >> 31) | 0x80000000u);
    return ((unsigned long long)mu << 32) | (unsigned)(255 - idx);
}
// inverse of mkkey's value part (bit-exact)
__device__ __forceinline__ float keyval(unsigned long long k) {
    unsigned mu = (unsigned)(k >> 32);
    unsigned u = (mu & 0x80000000u) ? (mu ^ 0x80000000u) : ~mu;
    return __uint_as_float(u);
}

// wave-wide exact 16th-largest key via ballot-radix bit search.
// Keys must be distinct across the 64 lanes (guaranteed by the index
// tiebreak). Only bits [63:32] and [7:0] can be set in any key, so the
// scan covers exactly those 40 bits. Invariant: count(key >= T) >= 16;
// greedy MSB acceptance builds T = the 16th-largest key exactly.
__device__ __forceinline__ unsigned long long sel16(unsigned long long k) {
    unsigned long long T = 0;
#pragma unroll
    for (int b = 63; b >= 32; --b) {
        unsigned long long C = T | (1ULL << b);
        if (__popcll(__ballot(k >= C)) >= 16) T = C;
    }
#pragma unroll
    for (int b = 7; b >= 0; --b) {
        unsigned long long C = T | (1ULL << b);
        if (__popcll(__ballot(k >= C)) >= 16) T = C;
    }
    return T;
}

// async global->LDS, 16B per lane (m97 ladder step)
__device__ __forceinline__ void gload16(const unsigned short* g, unsigned short* l) {
    __builtin_amdgcn_global_load_lds(
        (const __attribute__((address_space(1))) void*)g,
        (__attribute__((address_space(3))) void*)l, 16, 0, 0);
}

// combo-candidate table: (i,j) with (i+1)*(j+1) <= 16 encoded as i*16+j.
// Any combo outside this set has >= 16 strictly-greater keys (dominance +
// strict tiebreak), so the exact top-16 of the 256 sums lies inside it.
__device__ __constant__ unsigned char qtab[64] = {
    0, 1, 2, 3, 4, 5, 6, 7, 8, 9, 10, 11, 12, 13, 14, 15,   // i=0
    16, 17, 18, 19, 20, 21, 22, 23,                          // i=1
    32, 33, 34, 35, 36,                                      // i=2
    48, 49, 50, 51,                                          // i=3
    64, 65, 66,                                              // i=4
    80, 81, 96, 97, 112, 113,                                // i=5,6,7
    128, 144, 160, 176, 192, 208, 224, 240,                  // i=8..15
    0, 0, 0, 0, 0, 0, 0, 0, 0, 0, 0, 0, 0, 0};               // pad

// ---------------- fp32 -> bf16 convert (8 elems/thread) ----------------
__global__ void cvt_bf16(const float* __restrict__ src,
                         unsigned short* __restrict__ dst, int n8) {
    int i = blockIdx.x * blockDim.x + threadIdx.x;
    if (i >= n8) return;
    const float4* s4 = (const float4*)src;
    float4 a = s4[2 * i], b = s4[2 * i + 1];
    union { unsigned short u[8]; uint4 v; } r;
    r.u[0] = f2bf(a.x); r.u[1] = f2bf(a.y); r.u[2] = f2bf(a.z); r.u[3] = f2bf(a.w);
    r.u[4] = f2bf(b.x); r.u[5] = f2bf(b.y); r.u[6] = f2bf(b.z); r.u[7] = f2bf(b.w);
    ((uint4*)dst)[i] = r.v;
}

// ------- fp32 (1024x512) -> K-concat hi/lo pack (1024x1536 bf16) -------
// MODE 0 (Q):  dst row = [hi | hi | lo]
// MODE 1 (Wq): dst row = [hi | lo | hi]
template <int MODE>
__global__ void cvt_pack(const float* __restrict__ src,
                         unsigned short* __restrict__ dst) {
    int i = blockIdx.x * blockDim.x + threadIdx.x;  // float4 idx over 1024x512
    if (i >= 131072) return;
    int r = i >> 7, c4 = i & 127;
    float4 a = ((const float4*)src)[i];
    union { unsigned short u[4]; uint2 v; } rh, rl;
    float x[4] = {a.x, a.y, a.z, a.w};
#pragma unroll
    for (int j = 0; j < 4; j++) {
        unsigned short h = f2bf(x[j]);
        rh.u[j] = h;
        rl.u[j] = f2bf(x[j] - bf2f(h));
    }
    uint2* A2 = (uint2*)dst;                 // row stride 1536 shorts = 384 uint2
    A2[r * 384 + c4] = rh.v;
    A2[r * 384 + 128 + c4] = (MODE == 0) ? rh.v : rl.v;
    A2[r * 384 + 256 + c4] = (MODE == 0) ? rl.v : rh.v;
}

// ------- w_up half (32768 x 512) fp32 -> WuTh (512 x 32768) bf16 -------
// v2: 64x64 tiles, float4 global loads (256B segments), uint4 packed bf16
// stores (128B segments). LDS stride 65 floats: both phases 2-way = free.
__global__ void transpose_wu(const float* __restrict__ wu,
                             unsigned short* __restrict__ wuT, int e0base) {
    __shared__ float tile[64][65];
    int d0 = blockIdx.x * 64;          // 8 d-blocks
    int e0 = blockIdx.y * 64;          // 512 e-blocks per half
    int tid = threadIdx.x;

    int lr = tid >> 4;                 // 0..15 (e row within pass)
    int lc = tid & 15;                 // float4 col (4 d each)
#pragma unroll
    for (int p = 0; p < 4; p++) {
        int e = lr + 16 * p;
        float4 v = *(const float4*)&wu[(size_t)(e0base + e0 + e) * DIM + d0 + lc * 4];
        tile[e][lc * 4 + 0] = v.x;
        tile[e][lc * 4 + 1] = v.y;
        tile[e][lc * 4 + 2] = v.z;
        tile[e][lc * 4 + 3] = v.w;
    }
    __syncthreads();

    int dr = tid >> 3;                 // 0..31 (d row within pass)
    int ec = tid & 7;                  // e-group (8 e each)
#pragma unroll
    for (int p = 0; p < 2; p++) {
        int d = dr + 32 * p;
        union { unsigned short u[8]; uint4 v; } r;
#pragma unroll
        for (int k = 0; k < 8; k++) r.u[k] = f2bf(tile[ec * 8 + k][d]);
        *(uint4*)&wuT[(size_t)(d0 + d) * 32768 + e0 + ec * 8] = r.v;
    }
}

// ---------------- generic bf16 GEMM  C = A(MxK) * B(NxK)^T ----------------
// 128x128 tile, BK=64, 256 threads. global_load_lds width-16 staging,
// XOR source-swizzle (kchunk = slot ^ (row&7)) for conflict-free ds_read_b128.
// XCD-aware bijective block swizzle (T1): consecutive dispatched blocks land
// round-robin on the 8 XCDs; remap so each XCD gets a CONTIGUOUS logical
// chunk -> the 8 row-blocks sharing one B stripe hit the SAME XCD L2.
// Requires total blocks % 8 == 0 (all our grids: 64, 2048, 1024).
// EPI: 0 = plain store fp32 (qh)
//      1 = relu(acc)*scale[col], store bf16 (C tile); scale = w (pre-offset)
//      4 = store bf16 partial at slice bz (split-K, no atomics)
template <int EPI>
__global__ __launch_bounds__(256, 4) void gemm_bt(
    const unsigned short* __restrict__ A, int lda,
    const unsigned short* __restrict__ B, int ldb,
    int kIters,
    float* __restrict__ outF, unsigned short* __restrict__ outB, int ldc,
    const float* __restrict__ scale, size_t sliceStride) {
    __shared__ __align__(16) unsigned short As[128 * 64];
    __shared__ __align__(16) unsigned short Bs[128 * 64];

    // ---- T1 XCD swizzle ----
    int nwg = gridDim.x * gridDim.y * gridDim.z;
    int flat = blockIdx.x + gridDim.x * (blockIdx.y + gridDim.y * blockIdx.z);
    int swz;
    if ((nwg & 7) == 0) {
        int chunk = nwg >> 3;
        swz = (flat & 7) * chunk + (flat >> 3);
    } else {
        swz = flat;
    }
    int bx = swz % gridDim.x;
    int tmp = swz / gridDim.x;
    int by = tmp % gridDim.y;
    int bz = tmp / gridDim.y;

    int tid = threadIdx.x;
    int lane = tid & 63, wave = tid >> 6;
    int wm = (wave >> 1) * 64, wn = (wave & 1) * 64;
    int row0 = bx * 128, col0 = by * 128;
    size_t k00 = (size_t)bz * kIters * 64;           // split-K offset

    int rr = tid >> 3;
    int ss = tid & 7;
    int kb = ss ^ (rr & 7);
    const unsigned short* Ab = A + (size_t)(row0 + rr) * lda + k00 + kb * 8;
    const unsigned short* Bb = B + (size_t)(col0 + rr) * ldb + k00 + kb * 8;
    unsigned short* Asw = As + (size_t)tid * 8;      // lane-linear LDS dest
    unsigned short* Bsw = Bs + (size_t)tid * 8;

    f32x4 acc[4][4];
#pragma unroll
    for (int i = 0; i < 4; i++)
#pragma unroll
        for (int j = 0; j < 4; j++) acc[i][j] = 0.f;

    for (int kt = 0; kt < kIters; ++kt) {
        __syncthreads();                              // LDS consumers done
#pragma unroll
        for (int i = 0; i < 4; i++)
            gload16(Ab + (size_t)(32 * i) * lda + kt * 64, Asw + i * 2048);
#pragma unroll
        for (int i = 0; i < 4; i++)
            gload16(Bb + (size_t)(32 * i) * ldb + kt * 64, Bsw + i * 2048);
        __syncthreads();                              // vmcnt(0) drained here
#pragma unroll
        for (int ks = 0; ks < 2; ks++) {
            bf16x8 af[4], bfr[4];
#pragma unroll
            for (int i = 0; i < 4; i++) {
                int m = wm + i * 16 + (lane & 15);
                int kq = ks * 4 + (lane >> 4);
                af[i]  = *(const bf16x8*)(As + m * 64 + ((kq ^ (m & 7)) * 8));
                int n = wn + i * 16 + (lane & 15);
                bfr[i] = *(const bf16x8*)(Bs + n * 64 + ((kq ^ (n & 7)) * 8));
            }
#pragma unroll
            for (int i = 0; i < 4; i++)
#pragma unroll
                for (int j = 0; j < 4; j++)
                    acc[i][j] = __builtin_amdgcn_mfma_f32_16x16x32_bf16(
                        af[i], bfr[j], acc[i][j], 0, 0, 0);
        }
    }

    // epilogue: D[row=(lane>>4)*4+r][col=lane&15] per 16x16 tile (m89-verified)
#pragma unroll
    for (int i = 0; i < 4; i++) {
        int rbase = row0 + wm + i * 16 + (lane >> 4) * 4;
#pragma unroll
        for (int j = 0; j < 4; j++) {
            int c = col0 + wn + j * 16 + (lane & 15);
#pragma unroll
            for (int r2 = 0; r2 < 4; r2++) {
                float v = acc[i][j][r2];
                int row = rbase + r2;
                if (EPI == 0) {
                    outF[(size_t)row * ldc + c] = v;
                } else if (EPI == 1) {
                    outB[(size_t)row * ldc + c] = f2bf(fmaxf(v, 0.f) * scale[c]);
                } else {  // EPI == 4: bf16 split-K partial
                    outB[(size_t)bz * sliceStride + (size_t)row * ldc + c] =
                        f2bf(v);
                }
            }
        }
    }
}

// ---------------- sum 64 bf16 split-K partial slices -> out ----------------
__global__ void reduce_part(const unsigned short* __restrict__ part,
                            float* __restrict__ out) {
    int i = blockIdx.x * blockDim.x + threadIdx.x;   // 8-elem group, 65536 total
    const uint4* p4 = (const uint4*)part;            // 8 bf16 per uint4
    float s[8];
#pragma unroll
    for (int j = 0; j < 8; j++) s[j] = 0.f;
    for (int sl = 0; sl < 64; sl++) {
        uint4 t = p4[(size_t)sl * 65536 + i];
        unsigned uu[4] = {t.x, t.y, t.z, t.w};
#pragma unroll
        for (int j = 0; j < 4; j++) {
            s[2 * j]     += bf2f((unsigned short)(uu[j] & 0xffff));
            s[2 * j + 1] += bf2f((unsigned short)(uu[j] >> 16));
        }
    }
    float4* o4 = (float4*)out;
    o4[2 * i]     = make_float4(s[0], s[1], s[2], s[3]);
    o4[2 * i + 1] = make_float4(s[4], s[5], s[6], s[7]);
}

// ---------------- dense scores: S[nt][h][half][e] = q . k  (fp32) ----------
// block = (token-tile of 16, h, half), 256 threads = one e each.
// Key row (64 f32) lives in 16 float4 registers (issued up-front, pipelined);
// q-tile (16x64 +bias) staged in LDS, read as broadcasts.
// Accumulation expression order matches the original fused kernel exactly.
__global__ __launch_bounds__(256) void score_all(
    const float* __restrict__ qh, const float* __restrict__ bq,
    const float* __restrict__ keys, float* __restrict__ S) {
    int t0 = blockIdx.x * 16;
    int h  = blockIdx.y;
    int half = blockIdx.z;
    int tid = threadIdx.x;                       // e index

    __shared__ __align__(16) float qs[16 * 64];

    // 16 independent global loads: this thread's key row
    const float4* krow =
        (const float4*)(keys + (size_t)((h * 2 + half) * EXP + tid) * HALFD);
    float4 kreg[16];
#pragma unroll
    for (int c = 0; c < 16; c++) kreg[c] = krow[c];

    // stage q tile with bias folded in: thread i -> t=i>>4, c4=i&15
    {
        int t = tid >> 4, c4 = tid & 15;
        const float4* qsrc =
            (const float4*)(qh + (size_t)(t0 + t) * HDK + h * DKH + half * HALFD);
        const float4* bsrc = (const float4*)(bq + h * DKH + half * HALFD);
        float4 qv = qsrc[c4], bv = bsrc[c4];
        ((float4*)qs)[t * 16 + c4] =
            make_float4(qv.x + bv.x, qv.y + bv.y, qv.z + bv.z, qv.w + bv.w);
    }
    __syncthreads();

    float acc[16];
#pragma unroll
    for (int t = 0; t < 16; t++) acc[t] = 0.f;
#pragma unroll
    for (int c = 0; c < 16; c++) {
        float4 kv = kreg[c];
#pragma unroll
        for (int t = 0; t < 16; t++) {
            float4 qv = ((const float4*)qs)[t * 16 + c];   // LDS broadcast
            acc[t] += kv.x * qv.x + kv.y * qv.y + kv.z * qv.z + kv.w * qv.w;
        }
    }

#pragma unroll
    for (int t = 0; t < 16; t++)
        S[(size_t)(((t0 + t) * NH + h) * 2 + half) * EXP + tid] = acc[t];
}

// ------- exact hierarchical rank-based top-k + softmax (scores in) -------
// v3: phase 1 has ZERO LDS traffic — each wave's 64 segment keys live in its
// 64 lanes; top-16 selected via ballot-radix threshold (sel16) and compacted
// to c1k/c2k by ballot-prefix position (order irrelevant: phase 2 re-ranks).
// Values/indices decode bit-exactly from the keys. Phases 3/4 as v2
// (50-candidate dominance set, wave 0 only). 2 barriers total.
__global__ __launch_bounds__(256) void topk_sel(
    const float* __restrict__ S, float* __restrict__ w) {
    int nt = blockIdx.x, h = blockIdx.y;
    int tid = threadIdx.x;
    int lane = tid & 63, wv = tid >> 6;

    __shared__ __align__(16) unsigned long long c1k[64], c2k[64];
    __shared__ float t1v[16], t2v[16];
    __shared__ int   t1i[16], t2i[16];
    __shared__ __align__(16) unsigned long long ck[64];
    __shared__ float selv[16];
    __shared__ int   seli[16];

    // scores precomputed by score_all (coalesced 1KB per half per block)
    float v1 = S[(size_t)((nt * NH + h) * 2 + 0) * EXP + tid];
    float v2 = S[(size_t)((nt * NH + h) * 2 + 1) * EXP + tid];
    unsigned long long k1 = mkkey(v1, tid);
    unsigned long long k2 = mkkey(v2, tid);

    // phase 1: wave-local exact top-16 by ballot-radix (no LDS reads)
    {
        unsigned long long T1 = sel16(k1);
        unsigned long long m1 = __ballot(k1 >= T1);        // exactly 16 set
        if (k1 >= T1)
            c1k[wv * 16 + __popcll(m1 & ((1ULL << lane) - 1))] = k1;
        unsigned long long T2 = sel16(k2);
        unsigned long long m2 = __ballot(k2 >= T2);
        if (k2 >= T2)
            c2k[wv * 16 + __popcll(m2 & ((1ULL << lane) - 1))] = k2;
    }
    __syncthreads();

    // phase 2: merge 64 candidates -> global top-16 (wave0: s1, wave1: s2)
    if (wv < 2) {
        const unsigned long long* ak = wv ? c2k : c1k;
        unsigned long long mk = ak[lane];
        int r = 0;
#pragma unroll 4
        for (int j = 0; j < 64; j += 2) {
            ulonglong2 p = *(const ulonglong2*)&ak[j];
            r += (p.x > mk);
            r += (p.y > mk);
        }
        if (r < 16) {
            float v = keyval(mk);
            int e = 255 - (int)(mk & 0xff);
            if (wv == 0) { t1v[r] = v; t1i[r] = e; }
            else         { t2v[r] = v; t2i[r] = e; }
        }
    }
    __syncthreads();

    // wave 0 alone: exact top-16 of the 256 combo sums via the 50-candidate
    // dominance set, then softmax + scatter. t1v/t2v are sorted desc (indexed
    // by rank), so any combo outside {(i+1)(j+1)<=16} has >=16 strictly
    // greater keys (componentwise-dominating combos have lower flat index ->
    // strictly greater mkkey on value ties). Rank within the 50 == global rank
    // for the true top-16; non-top-16 candidates see all 16 winners in-set.
    if (wv == 0) {
        int qq = (int)qtab[lane];
        bool act = lane < 50;
        float cval = t1v[qq >> 4] + t2v[qq & 15];
        unsigned long long k = act ? mkkey(cval, qq) : 0ULL;  // pad keys lose
        ck[lane] = k;
        asm volatile("s_waitcnt lgkmcnt(0)" ::: "memory");    // in-wave visibility
        int r = 0;
#pragma unroll 5
        for (int j = 0; j < 50; j += 2) {
            ulonglong2 p = *(const ulonglong2*)&ck[j];
            r += (p.x > k);
            r += (p.y > k);
        }
        if (act && r < 16) {
            selv[r] = cval;
            seli[r] = t1i[qq >> 4] * EXP + t2i[qq & 15];
        }
        asm volatile("s_waitcnt lgkmcnt(0)" ::: "memory");    // selv/seli visible
        if (lane < 16) {
            float val = selv[lane];
            float mx = selv[0];
#pragma unroll
            for (int j = 1; j < 16; j++) mx = fmaxf(mx, selv[j]);
            float sm = 0.f;
#pragma unroll
            for (int j = 0; j < 16; j++) sm += __expf(selv[j] - mx);
            atomicAdd(&w[seli[lane]], __expf(val - mx) / sm);
        }
    }
}

// ---------------- launch ----------------
extern "C" void kernel_launch(void* const* d_in, const int* in_sizes, int n_in,
                              void* d_out, int out_size, void* d_ws, size_t ws_size,
                              hipStream_t stream) {
    const float* queries = (const float*)d_in[0];   // (2,512,512)
    const float* Wq      = (const float*)d_in[1];   // (1024,512)
    const float* bq      = (const float*)d_in[2];   // (1024)
    const float* keys    = (const float*)d_in[3];   // (8,2,256,64)
    const float* wd      = (const float*)d_in[4];   // (65536,512)
    const float* wu      = (const float*)d_in[5];   // (65536,512)
    float* out = (float*)d_out;                     // (2,512,512) fp32

    // workspace layout (196 MB)
    uint8_t* ws = (uint8_t*)d_ws;
    const size_t MB = 1048576;
    unsigned short* Qcat  = (unsigned short*)(ws);            // 0..3 MB (1024x1536)
    float*          w     = (float*)(ws + 3 * MB);            // 3..3.25 MB
    unsigned short* Wdh   = (unsigned short*)(ws + 4 * MB);   // 4..36 MB (32768x512)
    unsigned short* WuTh  = (unsigned short*)(ws + 36 * MB);  // 36..68 MB (512x32768)
    unsigned short* Cb    = (unsigned short*)(ws + 68 * MB);  // 68..132 MB (1024x32768)
    unsigned short* Ppart = (unsigned short*)(ws + 132 * MB); // 132..196 MB (64 slices bf16)
    // dead-after-score buffers alias the Ppart region (stream-ordered safe)
    unsigned short* Wqcat = (unsigned short*)(ws + 132 * MB); // 3 MB
    float*          qh    = (float*)(ws + 135 * MB);          // 4 MB
    float*          S     = (float*)(ws + 139 * MB);          // 16 MB scores

    hipMemsetAsync(w, 0, EE * sizeof(float), stream);

    cvt_pack<0><<<512, 256, 0, stream>>>(queries, Qcat);
    cvt_pack<1><<<512, 256, 0, stream>>>(Wq, Wqcat);

    // qh = Q @ Wq^T in ~fp32 via single K=1536 concat GEMM (bias in score_all)
    gemm_bt<0><<<dim3(8, 8, 1), 256, 0, stream>>>(
        Qcat, 1536, Wqcat, 1536, 24, qh, nullptr, HDK, nullptr, 0);

    // dense fp32 scores, then exact top-k + softmax -> w[e]
    score_all<<<dim3(64, NH, 2), 256, 0, stream>>>(qh, bq, keys, S);
    topk_sel<<<dim3(NTOK, NH), 256, 0, stream>>>(S, w);

    // big GEMMs per e-half; converts reuse 32 MB buffers inside the loop
    for (int sp = 0; sp < 2; sp++) {
        cvt_bf16<<<8192, 256, 0, stream>>>(wd + (size_t)sp * 16777216, Wdh, 2097152);
        // C[t,e] = relu(Q . wd[e]) * w[e]   (M=1024, N=32768, K=512)
        gemm_bt<1><<<dim3(8, 256, 1), 256, 0, stream>>>(
            Qcat, 1536, Wdh, DIM, 8, nullptr, Cb, 32768, w + (size_t)sp * 32768, 0);
        transpose_wu<<<dim3(8, 512), 256, 0, stream>>>(wu, WuTh, sp * 32768);
        // partial[z][t,d] = C[t,z-slice] . WuT[d,z-slice]  (split-K=32/half, bf16)
        gemm_bt<4><<<dim3(8, 4, 32), 256, 0, stream>>>(
            Cb, 32768, WuTh, 32768, 16, nullptr,
            Ppart + (size_t)sp * 32 * 524288, DIM, nullptr, 524288);
    }
    // out = sum of 64 bf16 partial slices
    reduce_part<<<256, 256, 0, stream>>>(Ppart, out);
}